// Round 11
// baseline (6404.572 us; speedup 1.0000x reference)
//
#include <hip/hip_runtime.h>
#include <stdint.h>

// RNN_Stack: 3-layer leaky-integrator RNN, T=512, B=256, I=64, N=512, TAU=2.
//
// Round-20 = round-19's proven per-wave engine (16 cols/wave, 128 VGPR, the
// round-10 win) with the communication graph halved: NCT 4 -> 2.
//   - 96 blocks = 3 lay x 16 rg x 2 halves, 1024 thr (16 waves x 16 cols).
//   - join degree 12 -> 5: q-join 1 sibling (was 3+self via 4 flags),
//     p-join 2 upstream halves (was 4), backpressure 2 (was 4).
//   - fabric clients halve (96 blocks issuing staging/flags per step).
//   - staging: uniform 2 x 16B loads/thread (q full-width incl. own half
//     re-read from own slot -- drained pre-publish, LLC-visible), per-lane
//     cndmask-selected slot offsets, single saddr (ring base).
//   Protocol semantics (monotone counters, RD=8 ring) unchanged from the
//   proven round-1/round-19 skeleton.

#define TS    512
#define BB    256
#define NN    512
#define MR    16     // rows per block
#define NRG   16     // rowgroups
#define NHF   2      // column halves per layer
#define RD    8      // ring depth (steps)
#define SLOTS 4096   // shorts per ring slot (MR x 256)

// swizzled short-index of 16B-chunk c (0..63) in row r (0..15)
#define SW(r, c) (((r) << 9) + ((((c) ^ ((r) & 7))) << 3))

typedef __attribute__((ext_vector_type(8))) short s8v;    // 8 bf16 (4 VGPR)
typedef __attribute__((ext_vector_type(4))) float f4v;    // 4 f32
typedef __attribute__((ext_vector_type(4))) unsigned int u4v;

#define MFMA16(a, b, c) __builtin_amdgcn_mfma_f32_16x16x32_bf16((a), (b), (c), 0, 0, 0)

__device__ __forceinline__ short f2bf(float f) {  // RNE f32 -> bf16 bits
  union { float f; unsigned u; } v; v.f = f;
  unsigned u = v.u;
  u += 0x7fffu + ((u >> 16) & 1u);
  return (short)(u >> 16);
}

__device__ __forceinline__ s8v pack8(f4v a, f4v b) {
  s8v v;
  v[0] = f2bf(a[0]); v[1] = f2bf(a[1]); v[2] = f2bf(a[2]); v[3] = f2bf(a[3]);
  v[4] = f2bf(b[0]); v[5] = f2bf(b[1]); v[6] = f2bf(b[2]); v[7] = f2bf(b[3]);
  return v;
}

__device__ __forceinline__ void waitvm0() {
  asm volatile("s_waitcnt vmcnt(0)" ::: "memory");
}

__device__ __forceinline__ void stg_sc1_b16(unsigned short* p, unsigned v) {
  asm volatile("global_store_short %0, %1, off sc1" :: "v"(p), "v"(v) : "memory");
}
// agent-scope atomics (LLC level) -- the known-good cross-XCD path.
__device__ __forceinline__ unsigned agent_ld(const unsigned* p) {
  return __hip_atomic_load(p, __ATOMIC_RELAXED, __HIP_MEMORY_SCOPE_AGENT);
}
__device__ __forceinline__ void agent_st(unsigned* p, unsigned v) {
  __hip_atomic_store(p, v, __ATOMIC_RELAXED, __HIP_MEMORY_SCOPE_AGENT);
}

// Sync batched sc1 loads, saddr form (single base = ring; 32-bit voffsets).
__device__ __forceinline__ void ld2_sync(u4v o[2],
    unsigned vq, unsigned vp, const unsigned short* ringbase) {
  asm volatile(
      "global_load_dwordx4 %0, %2, %4 sc1\n\t"
      "global_load_dwordx4 %1, %3, %4 sc1\n\t"
      "s_waitcnt vmcnt(0)"
      : "=&v"(o[0]), "=&v"(o[1])
      : "v"(vq), "v"(vp), "s"(ringbase)
      : "memory");
}
__device__ __forceinline__ void ld1_sync(u4v o[1],
    unsigned voff, const unsigned short* ringbase) {
  asm volatile(
      "global_load_dwordx4 %0, %1, %2 sc1\n\t"
      "s_waitcnt vmcnt(0)"
      : "=&v"(o[0])
      : "v"(voff), "s"(ringbase)
      : "memory");
}

__global__ __launch_bounds__(1024, 1) void rnn_pipe(
    const float* __restrict__ data, const float* __restrict__ h0,
    const float* __restrict__ Win,  const float* __restrict__ b_in,
    const float* __restrict__ Whh,  const float* __restrict__ b_hh,
    const float* __restrict__ Whi,  const float* __restrict__ b_hi,
    unsigned short* __restrict__ ring, unsigned* __restrict__ cnt,
    float* __restrict__ hfinal)
{
  __shared__ __attribute__((aligned(16))) unsigned short qtile[MR * NN];
  __shared__ __attribute__((aligned(16))) unsigned short ptile[MR * NN];

  const int bi   = blockIdx.x;         // 0..95
  // XCD-clustered role mapping: 12 blocks (2 rg x 6 members) per XCD under
  // round-robin dispatch (round-1 measured: weight L2 locality win).
  const int x8   = bi & 7;
  const int rest = bi >> 3;            // 0..11
  const int hrg  = (rest >= 6) ? 1 : 0;
  const int m    = rest - hrg * 6;     // member 0..5 within the rowgroup
  const int rg   = x8 * 2 + hrg;
  const int lay  = m >> 1;             // 0..2
  const int hf   = m & 1;              // column half 0..1
  const int tid  = threadIdx.x;        // 0..1023
  const int wv   = tid >> 6;           // 0..15
  const int lane = tid & 63;
  const int lo   = lane & 15;
  const int q4   = lane >> 4;
  const int row0 = rg * MR;
  const int cl   = wv * 16 + lo;       // col within my 256-wide half
  const int col  = hf * 256 + cl;      // global col 0..511

  // ---- flags: prod[sidx], done[sidx] at 128B stride; sidx=(lay*16+rg)*2+hf
  const int sidx = (lay * NRG + rg) * NHF + hf;
  unsigned* selfprod = cnt + (size_t)sidx * 32;
  unsigned* selfdone = cnt + (size_t)(256 + sidx) * 32;

  // per-lane poll assignment: lane 0: q-join (sibling), 4-5: p-join (2 up),
  // 8-9: backpressure (2 down); others idle on a satisfied dummy.
  unsigned* pollptr = selfprod;
  int polltype = 0;
  if (lane == 0) {
    pollptr = cnt + (size_t)((lay * NRG + rg) * NHF + (1 - hf)) * 32;          polltype = 1;
  } else if (lane >= 4 && lane < 6 && lay > 0) {
    pollptr = cnt + (size_t)(((lay - 1) * NRG + rg) * NHF + (lane - 4)) * 32;  polltype = 2;
  } else if (lane >= 8 && lane < 10 && lay < 2) {
    pollptr = cnt + (size_t)(256 + ((lay + 1) * NRG + rg) * NHF + (lane - 8)) * 32;  polltype = 3;
  }

  // ---- weight preload: B-frag[k = kk*32 + q4*8 + j][col] ----
  s8v WH[16];               // Whh_lay (diag zeroed)      64 VGPR
  s8v WI[16];               // Whi_{lay-1} (lay>0)        64 VGPR
  s8v WX[2];                // Win (K=64)                  8 VGPR
  float biasv;
  f4v  hst;                 // f32 h-state, rows q4*4+r, col

  {
    const float* WmH = Whh + (size_t)lay * NN * NN;
    #pragma unroll
    for (int kk = 0; kk < 16; ++kk) {
      s8v v;
      #pragma unroll
      for (int j = 0; j < 8; ++j) {
        const int k = kk * 32 + q4 * 8 + j;
        float f = WmH[(size_t)k * NN + col];
        if (k == col) f = 0.f;            // forward() zeroes recurrent diag
        v[j] = f2bf(f);
      }
      WH[kk] = v;
    }
    if (lay > 0) {
      const float* WmI = Whi + (size_t)(lay - 1) * NN * NN;
      #pragma unroll
      for (int kk = 0; kk < 16; ++kk) {
        s8v v;
        #pragma unroll
        for (int j = 0; j < 8; ++j)
          v[j] = f2bf(WmI[(size_t)(kk * 32 + q4 * 8 + j) * NN + col]);
        WI[kk] = v;
      }
    }
    #pragma unroll
    for (int kk = 0; kk < 2; ++kk) {
      s8v v;
      #pragma unroll
      for (int j = 0; j < 8; ++j)
        v[j] = f2bf(Win[(size_t)(kk * 32 + q4 * 8 + j) * NN + col]);
      WX[kk] = v;
    }
    float b = b_hh[lay * NN + col] + b_in[col];
    if (lay > 0) b += b_hi[(lay - 1) * NN + col];
    biasv = b;
    #pragma unroll
    for (int r = 0; r < 4; ++r)
      hst[r] = h0[(size_t)lay * BB * NN + (size_t)(row0 + q4 * 4 + r) * NN + col];
  }

  // ring slot indices (x SLOTS shorts each)
  const int myring  = sidx * RD;
  const int sibring = ((lay * NRG + rg) * NHF + (1 - hf)) * RD;
  const int upring0 = (lay > 0) ? (((lay - 1) * NRG + rg) * NHF + 0) * RD : 0;
  const int upring1 = (lay > 0) ? (((lay - 1) * NRG + rg) * NHF + 1) * RD : 0;

  // staging geometry: thread tid handles full-width chunk (r = tid>>6,
  // c = tid&63); chunks c<32 are half-0 cols, c>=32 half-1.
  const int sg_r   = tid >> 6;
  const int sg_c   = tid & 63;
  const unsigned lstat = (unsigned)(sg_r * 512 + (sg_c & 31) * 16); // bytes in slot
  const int qmine  = ((sg_c >> 5) == hf);   // my half vs sibling half
  const int puse1  = (sg_c >> 5);           // upstream half 1 vs 0

  // ---- xa preload for t=0 ----
  f4v xa0, xa1, xa2, xa3;
  {
    const float* dsrc = data + ((size_t)0 * BB + row0 + lo) * 64 + q4 * 8;
    xa0 = *(const f4v*)(dsrc + 0);
    xa1 = *(const f4v*)(dsrc + 4);
    xa2 = *(const f4v*)(dsrc + 32);
    xa3 = *(const f4v*)(dsrc + 36);
  }

  for (int t = 0; t < TS; ++t) {
    // ---- x-part MFMAs BEFORE the poll (xa loaded under previous drain) ----
    f4v zero4 = {0.f, 0.f, 0.f, 0.f};
    f4v accQ = zero4;
    f4v accP = zero4;
    {
      s8v xv0 = pack8(xa0, xa1);
      s8v xv1 = pack8(xa2, xa3);
      accQ = MFMA16(xv0, WX[0], accQ);
      accQ = MFMA16(xv1, WX[1], accQ);
    }

    // ---- poll all join conditions in parallel across lanes ----
    unsigned tgt = 0;
    if (polltype == 1) tgt = (unsigned)t;                                  // q-join
    else if (polltype == 2) tgt = (unsigned)(t + 1);                       // p-join
    else if (polltype == 3 && t >= RD) tgt = (unsigned)(t - RD + 1);       // backpressure
    for (;;) {
      unsigned v = agent_ld(pollptr);
      if (__all((int)(v >= tgt))) break;
    }

    // ---- cooperative staging: ONE sync asm block, swizzled LDS writes ----
    {
      const unsigned qslot_my  = (unsigned)((myring  + ((t - 1) & (RD - 1))) * (SLOTS * 2));
      const unsigned qslot_sib = (unsigned)((sibring + ((t - 1) & (RD - 1))) * (SLOTS * 2));
      const unsigned pslot_0   = (unsigned)((upring0 + (t & (RD - 1))) * (SLOTS * 2));
      const unsigned pslot_1   = (unsigned)((upring1 + (t & (RD - 1))) * (SLOTS * 2));
      const unsigned vq = (qmine ? qslot_my : qslot_sib) + lstat;
      const unsigned vp = (puse1 ? pslot_1 : pslot_0) + lstat;
      if (t >= 1 && lay > 0) {
        u4v st[2];
        ld2_sync(st, vq, vp, ring);
        *(u4v*)(qtile + SW(sg_r, sg_c)) = st[0];
        *(u4v*)(ptile + SW(sg_r, sg_c)) = st[1];
      } else if (t >= 1) {
        u4v st[1];
        ld1_sync(st, vq, ring);
        *(u4v*)(qtile + SW(sg_r, sg_c)) = st[0];
      } else if (lay > 0) {
        u4v st[1];
        ld1_sync(st, vp, ring);
        *(u4v*)(ptile + SW(sg_r, sg_c)) = st[0];
      }
    }
    __syncthreads();   // staging visible to all waves
    if (tid == 0 && lay > 0)   // upstream slot t consumed into LDS
      agent_st(selfdone, (unsigned)(t + 1));

    // ---- MFMA phase: q + p from swizzled LDS (t=0 q from h0) ----
    if (lay > 0) {
      #pragma unroll
      for (int kk = 0; kk < 16; ++kk) {
        s8v av = *(const s8v*)(ptile + SW(lo, kk * 4 + q4));
        accP = MFMA16(av, WI[kk], accP);
      }
    }
    if (t == 0) {
      const float* hsrc = h0 + (size_t)lay * BB * NN + (size_t)(row0 + lo) * NN + q4 * 8;
      #pragma unroll
      for (int kk = 0; kk < 16; ++kk) {
        f4v a = *(const f4v*)(hsrc + kk * 32);
        f4v b = *(const f4v*)(hsrc + kk * 32 + 4);
        s8v av = pack8(a, b);
        accQ = MFMA16(av, WH[kk], accQ);
      }
    } else {
      #pragma unroll
      for (int kk = 0; kk < 16; ++kk) {
        s8v av = *(const s8v*)(qtile + SW(lo, kk * 4 + q4));
        accQ = MFMA16(av, WH[kk], accQ);
      }
    }

    // ---- combine + produce: n = lrelu(0.5*h + 0.5*(q+p+x+bias)) ----
    {
      unsigned short* rslot = ring + (size_t)(myring + (t & (RD - 1))) * SLOTS;
      #pragma unroll
      for (int r = 0; r < 4; ++r) {
        const int row = q4 * 4 + r;
        float v = 0.5f * hst[r] + 0.5f * (accQ[r] + accP[r] + biasv);
        v = (v >= 0.f) ? v : 0.01f * v;
        hst[r] = v;
        stg_sc1_b16(rslot + (size_t)row * 256 + cl,
                    (unsigned)(unsigned short)f2bf(v));
        if (lay == 2 && t == TS - 1)
          hfinal[(size_t)(row0 + row) * NN + col] = v;
      }
    }

    // ---- xa loads for t+1 (latency hidden under the store drain) ----
    {
      const int tn = (t + 1 < TS) ? t + 1 : t;
      const float* dsrc = data + ((size_t)tn * BB + row0 + lo) * 64 + q4 * 8;
      xa0 = *(const f4v*)(dsrc + 0);
      xa1 = *(const f4v*)(dsrc + 4);
      xa2 = *(const f4v*)(dsrc + 32);
      xa3 = *(const f4v*)(dsrc + 36);
    }
    waitvm0();         // drains payload stores (and xa loads)
    __syncthreads();   // every wave's stores drained -> publish
    if (tid == 0)
      agent_st(selfprod, (unsigned)(t + 1));
  }
}

// out[256,10] = hfinal @ Wfc + b_fc   (tiny f32 readout)
__global__ void readout_k(const float* __restrict__ hfinal, const float* __restrict__ Wfc,
                          const float* __restrict__ b_fc, float* __restrict__ out)
{
  const int row = blockIdx.x;
  const int lane = threadIdx.x;  // 64
  float a[10];
  #pragma unroll
  for (int c = 0; c < 10; ++c) a[c] = 0.f;
  for (int k = lane; k < NN; k += 64) {
    const float h = hfinal[(size_t)row * NN + k];
    const float* w = Wfc + (size_t)k * 10;
    #pragma unroll
    for (int c = 0; c < 10; ++c) a[c] += h * w[c];
  }
  #pragma unroll
  for (int off = 32; off > 0; off >>= 1) {
    #pragma unroll
    for (int c = 0; c < 10; ++c) a[c] += __shfl_down(a[c], off);
  }
  if (lane == 0) {
    #pragma unroll
    for (int c = 0; c < 10; ++c) out[row * 10 + c] = a[c] + b_fc[c];
  }
}

extern "C" void kernel_launch(void* const* d_in, const int* in_sizes, int n_in,
                              void* d_out, int out_size, void* d_ws, size_t ws_size,
                              hipStream_t stream) {
  (void)in_sizes; (void)n_in; (void)out_size; (void)ws_size;
  const float* data = (const float*)d_in[0];
  const float* h0   = (const float*)d_in[1];
  const float* Win  = (const float*)d_in[2];
  const float* b_in = (const float*)d_in[3];
  const float* Whh  = (const float*)d_in[4];
  const float* b_hh = (const float*)d_in[5];
  const float* Whi  = (const float*)d_in[6];
  const float* b_hi = (const float*)d_in[7];
  const float* Wfc  = (const float*)d_in[8];
  const float* b_fc = (const float*)d_in[9];

  // ws: rings (96 slots-sets x RD x 8KB = 6 MB) | flags 64KB | hfinal 512KB
  unsigned short* ring = (unsigned short*)d_ws;
  const size_t ring_bytes = (size_t)3 * NRG * NHF * RD * SLOTS * 2;  // 6 MB
  unsigned* cnt = (unsigned*)((char*)d_ws + ring_bytes);
  float* hfinal = (float*)((char*)d_ws + ring_bytes + 65536);

  hipMemsetAsync(cnt, 0, 65536, stream);   // flags MUST start at 0 (ws is poisoned)
  hipLaunchKernelGGL(rnn_pipe, dim3(96), dim3(1024), 0, stream,
                     data, h0, Win, b_in, Whh, b_hh, Whi, b_hi, ring, cnt, hfinal);
  hipLaunchKernelGGL(readout_k, dim3(256), dim3(64), 0, stream,
                     hfinal, Wfc, b_fc, (float*)d_out);
}

// Round 13
// 1987.390 us; speedup vs baseline: 3.2226x; 3.2226x over previous
//
#include <hip/hip_runtime.h>
#include <stdint.h>

// RNN_Stack: 3-layer leaky-integrator RNN, T=512, B=256, I=64, N=512, TAU=2.
//
// Round-22 = round-21 RESUBMISSION (round-12 bench died broker-side:
// "MI355X container failed twice"; no kernel signal). Kernel re-audited:
// flag addressing disjoint + in-bounds, quad-line publishes hit distinct
// dwords (no RMW), poll targets byte-identical to proven protocol, engine
// byte-identical to round-10 (1966 us, VGPR 128, no spill). Content:
//   - quad-packed flag lines: 4 sibling prod counters of a (lay,rg) in one
//     128B line -> q-join poller lanes coalesce to ONE LLC transaction
//     (13 polled lines/wave -> 3).
//   - idle poll lanes issue NO load (contribute v=tgt; previously 52 lanes
//     re-read a dummy line every poll iteration).
// NCT=2 topology closed (round-11: 512KB weights/block = whole CU register
// file -> VGPR 64, mass spill, 3.3x slower). NCT=4, 16 cols/wave optimal.
//   192 blocks = 16 rowgroups x 12 members; 512 thr, 2 waves/SIMD.

#define TS    512
#define BB    256
#define NN    512
#define MR    16     // rows per block
#define NRG   16     // rowgroups
#define NCT   4      // coltiles per layer
#define RD    8      // ring depth (steps)

// swizzled short-index of 16B-chunk c (0..63) in row r (0..15)
#define SW(r, c) (((r) << 9) + ((((c) ^ ((r) & 7))) << 3))

typedef __attribute__((ext_vector_type(8))) short s8v;    // 8 bf16 (4 VGPR)
typedef __attribute__((ext_vector_type(4))) float f4v;    // 4 f32
typedef __attribute__((ext_vector_type(4))) unsigned int u4v;

#define MFMA16(a, b, c) __builtin_amdgcn_mfma_f32_16x16x32_bf16((a), (b), (c), 0, 0, 0)

__device__ __forceinline__ short f2bf(float f) {  // RNE f32 -> bf16 bits
  union { float f; unsigned u; } v; v.f = f;
  unsigned u = v.u;
  u += 0x7fffu + ((u >> 16) & 1u);
  return (short)(u >> 16);
}

__device__ __forceinline__ s8v pack8(f4v a, f4v b) {
  s8v v;
  v[0] = f2bf(a[0]); v[1] = f2bf(a[1]); v[2] = f2bf(a[2]); v[3] = f2bf(a[3]);
  v[4] = f2bf(b[0]); v[5] = f2bf(b[1]); v[6] = f2bf(b[2]); v[7] = f2bf(b[3]);
  return v;
}

__device__ __forceinline__ void waitvm0() {
  asm volatile("s_waitcnt vmcnt(0)" ::: "memory");
}

__device__ __forceinline__ void stg_sc1_b16(unsigned short* p, unsigned v) {
  asm volatile("global_store_short %0, %1, off sc1" :: "v"(p), "v"(v) : "memory");
}
// agent-scope atomics (LLC level) -- the known-good cross-XCD path.
__device__ __forceinline__ unsigned agent_ld(const unsigned* p) {
  return __hip_atomic_load(p, __ATOMIC_RELAXED, __HIP_MEMORY_SCOPE_AGENT);
}
__device__ __forceinline__ void agent_st(unsigned* p, unsigned v) {
  __hip_atomic_store(p, v, __ATOMIC_RELAXED, __HIP_MEMORY_SCOPE_AGENT);
}

// Sync batched sc1 loads, saddr form (512-thread geometry: 2 chunks per
// thread per tile). Completed before the asm block exits.
__device__ __forceinline__ void ld4_dual(u4v o[4],
    unsigned vA, unsigned vB,
    const unsigned short* sq, const unsigned short* sp) {
  asm volatile(
      "global_load_dwordx4 %0, %4, %6 sc1\n\t"
      "global_load_dwordx4 %1, %5, %6 sc1\n\t"
      "global_load_dwordx4 %2, %4, %7 sc1\n\t"
      "global_load_dwordx4 %3, %5, %7 sc1\n\t"
      "s_waitcnt vmcnt(0)"
      : "=&v"(o[0]), "=&v"(o[1]), "=&v"(o[2]), "=&v"(o[3])
      : "v"(vA), "v"(vB), "s"(sq), "s"(sp)
      : "memory");
}
__device__ __forceinline__ void ld2_sync(u4v o[2],
    unsigned vA, unsigned vB, const unsigned short* sb) {
  asm volatile(
      "global_load_dwordx4 %0, %2, %4 sc1\n\t"
      "global_load_dwordx4 %1, %3, %4 sc1\n\t"
      "s_waitcnt vmcnt(0)"
      : "=&v"(o[0]), "=&v"(o[1])
      : "v"(vA), "v"(vB), "s"(sb)
      : "memory");
}

__global__ __launch_bounds__(512, 2) void rnn_pipe(
    const float* __restrict__ data, const float* __restrict__ h0,
    const float* __restrict__ Win,  const float* __restrict__ b_in,
    const float* __restrict__ Whh,  const float* __restrict__ b_hh,
    const float* __restrict__ Whi,  const float* __restrict__ b_hi,
    unsigned short* __restrict__ ring, unsigned* __restrict__ cnt,
    float* __restrict__ hfinal)
{
  __shared__ __attribute__((aligned(16))) unsigned short qtile[MR * NN];
  __shared__ __attribute__((aligned(16))) unsigned short ptile[MR * NN];

  const int bi   = blockIdx.x;
  // XCD-clustered role mapping (round-1 measured: weight L2 locality win).
  const int x8   = bi & 7;
  const int rr   = bi >> 3;            // 0..23
  const int half = (rr >= 12) ? 1 : 0;
  const int m    = rr - half * 12;     // member 0..11 within the rowgroup
  const int rg   = x8 * 2 + half;
  const int lay  = m >> 2;
  const int ct   = m & 3;
  const int tid  = threadIdx.x;        // 0..511
  const int wv   = tid >> 6;           // 0..7
  const int lane = tid & 63;
  const int lo   = lane & 15;
  const int q4   = lane >> 4;
  const int row0 = rg * MR;
  const int cw   = ct * 128 + wv * 16;   // this wave's 16-col base

  // ---- flags, quad-packed: one 128B line per (lay,rg) quad ----
  //   prod line idx = lay*NRG+rg       (dwords 0..3 = ct)
  //   done line idx = 64 + lay*NRG+rg  (dwords 0..3 = ct; written by lay>0)
  unsigned* prodline = cnt + (size_t)(lay * NRG + rg) * 32;
  unsigned* doneline = cnt + (size_t)(64 + lay * NRG + rg) * 32;

  // all-wave poll assignment: lanes 0-3 q-join (4 ct of own quad-line),
  // 4-7 p-join (upstream quad-line), 8-11 backpressure (downstream done
  // line). Idle lanes issue NO load (v=tgt).
  unsigned* pollptr = prodline;
  int polltype = 0;
  if (lane < 4) {
    pollptr = cnt + (size_t)(lay * NRG + rg) * 32 + lane;                    polltype = 1;
  } else if (lane >= 4 && lane < 8 && lay > 0) {
    pollptr = cnt + (size_t)((lay - 1) * NRG + rg) * 32 + (lane - 4);        polltype = 2;
  } else if (lane >= 8 && lane < 12 && lay < 2) {
    pollptr = cnt + (size_t)(64 + (lay + 1) * NRG + rg) * 32 + (lane - 8);   polltype = 3;
  }

  // ---- weight preload: B-frag[k = kk*32 + q4*8 + j][col = cw + lo] ----
  s8v WH[16];               // Whh_lay (diag zeroed)      64 VGPR
  s8v WI[16];               // Whi_{lay-1} (lay>0)        64 VGPR
  s8v WX[2];                // Win (K=64)                  8 VGPR
  float biasv;
  f4v  hst;                 // f32 h-state, rows q4*4+r, col cw+lo

  {
    const float* WmH = Whh + (size_t)lay * NN * NN;
    const int col = cw + lo;
    #pragma unroll
    for (int kk = 0; kk < 16; ++kk) {
      s8v v;
      #pragma unroll
      for (int j = 0; j < 8; ++j) {
        const int k = kk * 32 + q4 * 8 + j;
        float f = WmH[(size_t)k * NN + col];
        if (k == col) f = 0.f;            // forward() zeroes recurrent diag
        v[j] = f2bf(f);
      }
      WH[kk] = v;
    }
    if (lay > 0) {
      const float* WmI = Whi + (size_t)(lay - 1) * NN * NN;
      #pragma unroll
      for (int kk = 0; kk < 16; ++kk) {
        s8v v;
        #pragma unroll
        for (int j = 0; j < 8; ++j)
          v[j] = f2bf(WmI[(size_t)(kk * 32 + q4 * 8 + j) * NN + col]);
        WI[kk] = v;
      }
    }
    #pragma unroll
    for (int kk = 0; kk < 2; ++kk) {
      s8v v;
      #pragma unroll
      for (int j = 0; j < 8; ++j)
        v[j] = f2bf(Win[(size_t)(kk * 32 + q4 * 8 + j) * NN + col]);
      WX[kk] = v;
    }
    float b = b_hh[lay * NN + col] + b_in[col];
    if (lay > 0) b += b_hi[(lay - 1) * NN + col];
    biasv = b;
    #pragma unroll
    for (int r = 0; r < 4; ++r)
      hst[r] = h0[(size_t)lay * BB * NN + (size_t)(row0 + q4 * 4 + r) * NN + col];
  }

  const size_t myring = (size_t)(lay * NRG + rg) * RD;
  const size_t upring = (size_t)((lay - 1) * NRG + rg) * RD;

  // loop-invariant staging byte-offsets: chunk g = i*512 + tid (dense, 512 thr)
  unsigned voffA = (unsigned)((0 * 512 + tid) * 16);
  unsigned voffB = (unsigned)((1 * 512 + tid) * 16);
  const int gA_r = tid >> 6,           gA_c = tid & 63;
  const int gB_r = (512 + tid) >> 6,   gB_c = tid & 63;   // (512+tid)&63 == tid&63

  // ---- xa preload for t=0 (A-frag is wave-independent) ----
  f4v xa0, xa1, xa2, xa3;
  {
    const float* dsrc = data + ((size_t)0 * BB + row0 + lo) * 64 + q4 * 8;
    xa0 = *(const f4v*)(dsrc + 0);
    xa1 = *(const f4v*)(dsrc + 4);
    xa2 = *(const f4v*)(dsrc + 32);
    xa3 = *(const f4v*)(dsrc + 36);
  }

  for (int t = 0; t < TS; ++t) {
    // ---- x-part MFMAs BEFORE the poll (xa loaded under previous drain) ----
    f4v zero4 = {0.f, 0.f, 0.f, 0.f};
    f4v accQ = zero4;
    f4v accP = zero4;
    {
      s8v xv0 = pack8(xa0, xa1);
      s8v xv1 = pack8(xa2, xa3);
      accQ = MFMA16(xv0, WX[0], accQ);
      accQ = MFMA16(xv1, WX[1], accQ);
    }

    // ---- poll all join conditions in parallel across lanes ----
    unsigned tgt = 0;
    if (polltype == 1) tgt = (unsigned)t;                                  // q-join
    else if (polltype == 2) tgt = (unsigned)(t + 1);                       // p-join
    else if (polltype == 3 && t >= RD) tgt = (unsigned)(t - RD + 1);       // backpressure
    for (;;) {
      unsigned v = tgt;
      if (polltype) v = agent_ld(pollptr);
      if (__all((int)(v >= tgt))) break;
    }

    // ---- cooperative staging: ONE sync asm block, swizzled LDS writes ----
    {
      const unsigned short* qsrc = ring + (myring + ((t - 1) & (RD - 1))) * (MR * NN);
      const unsigned short* psrc = ring + (upring + (t & (RD - 1))) * (MR * NN);
      if (t >= 1 && lay > 0) {
        u4v st[4];
        ld4_dual(st, voffA, voffB, qsrc, psrc);
        *(u4v*)(qtile + SW(gA_r, gA_c)) = st[0];
        *(u4v*)(qtile + SW(gB_r, gB_c)) = st[1];
        *(u4v*)(ptile + SW(gA_r, gA_c)) = st[2];
        *(u4v*)(ptile + SW(gB_r, gB_c)) = st[3];
      } else if (t >= 1) {
        u4v st[2];
        ld2_sync(st, voffA, voffB, qsrc);
        *(u4v*)(qtile + SW(gA_r, gA_c)) = st[0];
        *(u4v*)(qtile + SW(gB_r, gB_c)) = st[1];
      } else if (lay > 0) {
        u4v st[2];
        ld2_sync(st, voffA, voffB, psrc);
        *(u4v*)(ptile + SW(gA_r, gA_c)) = st[0];
        *(u4v*)(ptile + SW(gB_r, gB_c)) = st[1];
      }
    }
    __syncthreads();   // staging visible to all waves
    if (tid == 0 && lay > 0)   // upstream slot t consumed into LDS
      agent_st(doneline + ct, (unsigned)(t + 1));

    // ---- MFMA phase: q + p from swizzled LDS (t=0 q from h0) ----
    if (lay > 0) {
      #pragma unroll
      for (int kk = 0; kk < 16; ++kk) {
        s8v av = *(const s8v*)(ptile + SW(lo, kk * 4 + q4));
        accP = MFMA16(av, WI[kk], accP);
      }
    }
    if (t == 0) {
      const float* hsrc = h0 + (size_t)lay * BB * NN + (size_t)(row0 + lo) * NN + q4 * 8;
      #pragma unroll
      for (int kk = 0; kk < 16; ++kk) {
        f4v a = *(const f4v*)(hsrc + kk * 32);
        f4v b = *(const f4v*)(hsrc + kk * 32 + 4);
        s8v av = pack8(a, b);
        accQ = MFMA16(av, WH[kk], accQ);
      }
    } else {
      #pragma unroll
      for (int kk = 0; kk < 16; ++kk) {
        s8v av = *(const s8v*)(qtile + SW(lo, kk * 4 + q4));
        accQ = MFMA16(av, WH[kk], accQ);
      }
    }

    // ---- combine + produce: n = lrelu(0.5*h + 0.5*(q+p+x+bias)) ----
    {
      unsigned short* rslot = ring + (myring + (t & (RD - 1))) * (MR * NN);
      const int col = cw + lo;
      #pragma unroll
      for (int r = 0; r < 4; ++r) {
        const int row = q4 * 4 + r;
        float v = 0.5f * hst[r] + 0.5f * (accQ[r] + accP[r] + biasv);
        v = (v >= 0.f) ? v : 0.01f * v;
        hst[r] = v;
        stg_sc1_b16(rslot + (size_t)row * NN + col,
                    (unsigned)(unsigned short)f2bf(v));
        if (lay == 2 && t == TS - 1)
          hfinal[(size_t)(row0 + row) * NN + col] = v;
      }
    }

    // ---- xa loads for t+1 (latency hidden under the store drain) ----
    {
      const int tn = (t + 1 < TS) ? t + 1 : t;
      const float* dsrc = data + ((size_t)tn * BB + row0 + lo) * 64 + q4 * 8;
      xa0 = *(const f4v*)(dsrc + 0);
      xa1 = *(const f4v*)(dsrc + 4);
      xa2 = *(const f4v*)(dsrc + 32);
      xa3 = *(const f4v*)(dsrc + 36);
    }
    waitvm0();         // drains payload stores (and xa loads)
    __syncthreads();   // every wave's stores drained -> publish
    if (tid == 0)
      agent_st(prodline + ct, (unsigned)(t + 1));
  }
}

// out[256,10] = hfinal @ Wfc + b_fc   (tiny f32 readout)
__global__ void readout_k(const float* __restrict__ hfinal, const float* __restrict__ Wfc,
                          const float* __restrict__ b_fc, float* __restrict__ out)
{
  const int row = blockIdx.x;
  const int lane = threadIdx.x;  // 64
  float a[10];
  #pragma unroll
  for (int c = 0; c < 10; ++c) a[c] = 0.f;
  for (int k = lane; k < NN; k += 64) {
    const float h = hfinal[(size_t)row * NN + k];
    const float* w = Wfc + (size_t)k * 10;
    #pragma unroll
    for (int c = 0; c < 10; ++c) a[c] += h * w[c];
  }
  #pragma unroll
  for (int off = 32; off > 0; off >>= 1) {
    #pragma unroll
    for (int c = 0; c < 10; ++c) a[c] += __shfl_down(a[c], off);
  }
  if (lane == 0) {
    #pragma unroll
    for (int c = 0; c < 10; ++c) out[row * 10 + c] = a[c] + b_fc[c];
  }
}

extern "C" void kernel_launch(void* const* d_in, const int* in_sizes, int n_in,
                              void* d_out, int out_size, void* d_ws, size_t ws_size,
                              hipStream_t stream) {
  (void)in_sizes; (void)n_in; (void)out_size; (void)ws_size;
  const float* data = (const float*)d_in[0];
  const float* h0   = (const float*)d_in[1];
  const float* Win  = (const float*)d_in[2];
  const float* b_in = (const float*)d_in[3];
  const float* Whh  = (const float*)d_in[4];
  const float* b_hh = (const float*)d_in[5];
  const float* Whi  = (const float*)d_in[6];
  const float* b_hi = (const float*)d_in[7];
  const float* Wfc  = (const float*)d_in[8];
  const float* b_fc = (const float*)d_in[9];

  // ws: rings (3 lay x 16 rg x RD x 16KB = 6 MB) | flags 64KB | hfinal 512KB
  unsigned short* ring = (unsigned short*)d_ws;
  const size_t ring_bytes = (size_t)3 * NRG * RD * MR * NN * 2;  // 6 MB
  unsigned* cnt = (unsigned*)((char*)d_ws + ring_bytes);
  float* hfinal = (float*)((char*)d_ws + ring_bytes + 65536);

  hipMemsetAsync(cnt, 0, 65536, stream);   // flags MUST start at 0 (ws is poisoned)
  hipLaunchKernelGGL(rnn_pipe, dim3(192), dim3(512), 0, stream,
                     data, h0, Win, b_in, Whh, b_hh, Whi, b_hi, ring, cnt, hfinal);
  hipLaunchKernelGGL(readout_k, dim3(256), dim3(64), 0, stream,
                     hfinal, Wfc, b_fc, (float*)d_out);
}

// Round 14
// 1985.230 us; speedup vs baseline: 3.2261x; 1.0011x over previous
//
#include <hip/hip_runtime.h>
#include <stdint.h>

// RNN_Stack: 3-layer leaky-integrator RNN, T=512, B=256, I=64, N=512, TAU=2.
//
// Round-23 = round-22 (best: 1957us; 512 thr, 8 waves x 16 cols, 128 VGPR,
// quad-packed flags) + P-PREFETCH: the p-join has RD-1 steps of slack
// (upstream runs ahead until backpressure binds), so in steady state the
// upstream tile for step t+1 is published long before needed. At step t's
// poll, lanes 4-7 capture (from the satisfying value, no extra load)
// whether prod_up >= t+2; if so the p-loads for t+1 are issued ASYNC after
// staging (latency hidden under MFMA+drain) and staged from registers at
// t+1 -- the blocking batch shrinks 32KB -> 16KB for lay>0 blocks (2/3 of
// all). Tied-operand s_waitcnt ("+v") guards the async regs. Miss ->
// existing blocking path (per-wave-uniform branch).
//   192 blocks = 16 rowgroups x 12 members; 512 thr, 2 waves/SIMD.

#define TS    512
#define BB    256
#define NN    512
#define MR    16     // rows per block
#define NRG   16     // rowgroups
#define NCT   4      // coltiles per layer
#define RD    8      // ring depth (steps)

// swizzled short-index of 16B-chunk c (0..63) in row r (0..15)
#define SW(r, c) (((r) << 9) + ((((c) ^ ((r) & 7))) << 3))

typedef __attribute__((ext_vector_type(8))) short s8v;    // 8 bf16 (4 VGPR)
typedef __attribute__((ext_vector_type(4))) float f4v;    // 4 f32
typedef __attribute__((ext_vector_type(4))) unsigned int u4v;

#define MFMA16(a, b, c) __builtin_amdgcn_mfma_f32_16x16x32_bf16((a), (b), (c), 0, 0, 0)

__device__ __forceinline__ short f2bf(float f) {  // RNE f32 -> bf16 bits
  union { float f; unsigned u; } v; v.f = f;
  unsigned u = v.u;
  u += 0x7fffu + ((u >> 16) & 1u);
  return (short)(u >> 16);
}

__device__ __forceinline__ s8v pack8(f4v a, f4v b) {
  s8v v;
  v[0] = f2bf(a[0]); v[1] = f2bf(a[1]); v[2] = f2bf(a[2]); v[3] = f2bf(a[3]);
  v[4] = f2bf(b[0]); v[5] = f2bf(b[1]); v[6] = f2bf(b[2]); v[7] = f2bf(b[3]);
  return v;
}

__device__ __forceinline__ void waitvm0() {
  asm volatile("s_waitcnt vmcnt(0)" ::: "memory");
}

__device__ __forceinline__ void stg_sc1_b16(unsigned short* p, unsigned v) {
  asm volatile("global_store_short %0, %1, off sc1" :: "v"(p), "v"(v) : "memory");
}
// agent-scope atomics (LLC level) -- the known-good cross-XCD path.
__device__ __forceinline__ unsigned agent_ld(const unsigned* p) {
  return __hip_atomic_load(p, __ATOMIC_RELAXED, __HIP_MEMORY_SCOPE_AGENT);
}
__device__ __forceinline__ void agent_st(unsigned* p, unsigned v) {
  __hip_atomic_store(p, v, __ATOMIC_RELAXED, __HIP_MEMORY_SCOPE_AGENT);
}

// Sync batched sc1 loads, saddr form (512-thread geometry: 2 chunks per
// thread per tile). Completed before the asm block exits.
__device__ __forceinline__ void ld4_dual(u4v o[4],
    unsigned vA, unsigned vB,
    const unsigned short* sq, const unsigned short* sp) {
  asm volatile(
      "global_load_dwordx4 %0, %4, %6 sc1\n\t"
      "global_load_dwordx4 %1, %5, %6 sc1\n\t"
      "global_load_dwordx4 %2, %4, %7 sc1\n\t"
      "global_load_dwordx4 %3, %5, %7 sc1\n\t"
      "s_waitcnt vmcnt(0)"
      : "=&v"(o[0]), "=&v"(o[1]), "=&v"(o[2]), "=&v"(o[3])
      : "v"(vA), "v"(vB), "s"(sq), "s"(sp)
      : "memory");
}
__device__ __forceinline__ void ld2_sync(u4v o[2],
    unsigned vA, unsigned vB, const unsigned short* sb) {
  asm volatile(
      "global_load_dwordx4 %0, %2, %4 sc1\n\t"
      "global_load_dwordx4 %1, %3, %4 sc1\n\t"
      "s_waitcnt vmcnt(0)"
      : "=&v"(o[0]), "=&v"(o[1])
      : "v"(vA), "v"(vB), "s"(sb)
      : "memory");
}
// Async pair: issue only, no wait. MUST be followed (before any read of o0/
// o1) by a tied-operand vmcnt(0) asm -- see pf_wait.
__device__ __forceinline__ void ld2_async(u4v& o0, u4v& o1,
    unsigned vA, unsigned vB, const unsigned short* sb) {
  asm volatile(
      "global_load_dwordx4 %0, %2, %4 sc1\n\t"
      "global_load_dwordx4 %1, %3, %4 sc1"
      : "=&v"(o0), "=&v"(o1)
      : "v"(vA), "v"(vB), "s"(sb)
      : "memory");
}
__device__ __forceinline__ void pf_wait(u4v& o0, u4v& o1) {
  asm volatile("s_waitcnt vmcnt(0)" : "+v"(o0), "+v"(o1) :: "memory");
}

__global__ __launch_bounds__(512, 2) void rnn_pipe(
    const float* __restrict__ data, const float* __restrict__ h0,
    const float* __restrict__ Win,  const float* __restrict__ b_in,
    const float* __restrict__ Whh,  const float* __restrict__ b_hh,
    const float* __restrict__ Whi,  const float* __restrict__ b_hi,
    unsigned short* __restrict__ ring, unsigned* __restrict__ cnt,
    float* __restrict__ hfinal)
{
  __shared__ __attribute__((aligned(16))) unsigned short qtile[MR * NN];
  __shared__ __attribute__((aligned(16))) unsigned short ptile[MR * NN];

  const int bi   = blockIdx.x;
  // XCD-clustered role mapping (round-1 measured: weight L2 locality win).
  const int x8   = bi & 7;
  const int rr   = bi >> 3;            // 0..23
  const int half = (rr >= 12) ? 1 : 0;
  const int m    = rr - half * 12;     // member 0..11 within the rowgroup
  const int rg   = x8 * 2 + half;
  const int lay  = m >> 2;
  const int ct   = m & 3;
  const int tid  = threadIdx.x;        // 0..511
  const int wv   = tid >> 6;           // 0..7
  const int lane = tid & 63;
  const int lo   = lane & 15;
  const int q4   = lane >> 4;
  const int row0 = rg * MR;
  const int cw   = ct * 128 + wv * 16;   // this wave's 16-col base

  // ---- flags, quad-packed: one 128B line per (lay,rg) quad ----
  //   prod line idx = lay*NRG+rg       (dwords 0..3 = ct)
  //   done line idx = 64 + lay*NRG+rg  (dwords 0..3 = ct; written by lay>0)
  unsigned* prodline = cnt + (size_t)(lay * NRG + rg) * 32;
  unsigned* doneline = cnt + (size_t)(64 + lay * NRG + rg) * 32;

  // all-wave poll assignment: lanes 0-3 q-join (4 ct of own quad-line),
  // 4-7 p-join (upstream quad-line), 8-11 backpressure (downstream done
  // line). Idle lanes issue NO load (v=tgt).
  unsigned* pollptr = prodline;
  int polltype = 0;
  if (lane < 4) {
    pollptr = cnt + (size_t)(lay * NRG + rg) * 32 + lane;                    polltype = 1;
  } else if (lane >= 4 && lane < 8 && lay > 0) {
    pollptr = cnt + (size_t)((lay - 1) * NRG + rg) * 32 + (lane - 4);        polltype = 2;
  } else if (lane >= 8 && lane < 12 && lay < 2) {
    pollptr = cnt + (size_t)(64 + (lay + 1) * NRG + rg) * 32 + (lane - 8);   polltype = 3;
  }

  // ---- weight preload: B-frag[k = kk*32 + q4*8 + j][col = cw + lo] ----
  s8v WH[16];               // Whh_lay (diag zeroed)      64 VGPR
  s8v WI[16];               // Whi_{lay-1} (lay>0)        64 VGPR
  s8v WX[2];                // Win (K=64)                  8 VGPR
  float biasv;
  f4v  hst;                 // f32 h-state, rows q4*4+r, col cw+lo

  {
    const float* WmH = Whh + (size_t)lay * NN * NN;
    const int col = cw + lo;
    #pragma unroll
    for (int kk = 0; kk < 16; ++kk) {
      s8v v;
      #pragma unroll
      for (int j = 0; j < 8; ++j) {
        const int k = kk * 32 + q4 * 8 + j;
        float f = WmH[(size_t)k * NN + col];
        if (k == col) f = 0.f;            // forward() zeroes recurrent diag
        v[j] = f2bf(f);
      }
      WH[kk] = v;
    }
    if (lay > 0) {
      const float* WmI = Whi + (size_t)(lay - 1) * NN * NN;
      #pragma unroll
      for (int kk = 0; kk < 16; ++kk) {
        s8v v;
        #pragma unroll
        for (int j = 0; j < 8; ++j)
          v[j] = f2bf(WmI[(size_t)(kk * 32 + q4 * 8 + j) * NN + col]);
        WI[kk] = v;
      }
    }
    #pragma unroll
    for (int kk = 0; kk < 2; ++kk) {
      s8v v;
      #pragma unroll
      for (int j = 0; j < 8; ++j)
        v[j] = f2bf(Win[(size_t)(kk * 32 + q4 * 8 + j) * NN + col]);
      WX[kk] = v;
    }
    float b = b_hh[lay * NN + col] + b_in[col];
    if (lay > 0) b += b_hi[(lay - 1) * NN + col];
    biasv = b;
    #pragma unroll
    for (int r = 0; r < 4; ++r)
      hst[r] = h0[(size_t)lay * BB * NN + (size_t)(row0 + q4 * 4 + r) * NN + col];
  }

  const size_t myring = (size_t)(lay * NRG + rg) * RD;
  const size_t upring = (size_t)((lay - 1) * NRG + rg) * RD;

  // loop-invariant staging byte-offsets: chunk g = i*512 + tid (dense, 512 thr)
  unsigned voffA = (unsigned)((0 * 512 + tid) * 16);
  unsigned voffB = (unsigned)((1 * 512 + tid) * 16);
  const int gA_r = tid >> 6,           gA_c = tid & 63;
  const int gB_r = (512 + tid) >> 6,   gB_c = tid & 63;   // (512+tid)&63 == tid&63

  // p-prefetch state (lay>0): regs for next step's p-chunks + wave-uniform flag
  u4v pf0 = {0, 0, 0, 0}, pf1 = {0, 0, 0, 0};
  int pfvalid = 0;

  // ---- xa preload for t=0 (A-frag is wave-independent) ----
  f4v xa0, xa1, xa2, xa3;
  {
    const float* dsrc = data + ((size_t)0 * BB + row0 + lo) * 64 + q4 * 8;
    xa0 = *(const f4v*)(dsrc + 0);
    xa1 = *(const f4v*)(dsrc + 4);
    xa2 = *(const f4v*)(dsrc + 32);
    xa3 = *(const f4v*)(dsrc + 36);
  }

  for (int t = 0; t < TS; ++t) {
    // ---- x-part MFMAs BEFORE the poll (xa loaded under previous drain) ----
    f4v zero4 = {0.f, 0.f, 0.f, 0.f};
    f4v accQ = zero4;
    f4v accP = zero4;
    {
      s8v xv0 = pack8(xa0, xa1);
      s8v xv1 = pack8(xa2, xa3);
      accQ = MFMA16(xv0, WX[0], accQ);
      accQ = MFMA16(xv1, WX[1], accQ);
    }

    // ---- poll all join conditions in parallel across lanes ----
    // p-lanes with a valid prefetch don't block (tgt=0) but still sample
    // fresh values so the NEXT step's prefetch decision stays live.
    unsigned tgt = 0;
    if (polltype == 1) tgt = (unsigned)t;                                  // q-join
    else if (polltype == 2 && !pfvalid) tgt = (unsigned)(t + 1);           // p-join
    else if (polltype == 3 && t >= RD) tgt = (unsigned)(t - RD + 1);       // backpressure
    unsigned v = tgt;
    for (;;) {
      if (polltype) v = agent_ld(pollptr);
      if (__all((int)(v >= tgt))) break;
    }
    // capture prefetch opportunity for step t+1 (its p-join needs >= t+2)
    const int pnext = (lay > 0 && t + 1 < TS)
        ? __all((int)((polltype == 2) ? (v >= (unsigned)(t + 2)) : 1)) : 0;

    // ---- cooperative staging: blocking batch + (optional) prefetched p ----
    {
      const unsigned short* qsrc = ring + (myring + ((t - 1) & (RD - 1))) * (MR * NN);
      const unsigned short* psrc = ring + (upring + (t & (RD - 1))) * (MR * NN);
      if (t >= 1 && lay > 0) {
        if (pfvalid) {
          u4v st[2];
          ld2_sync(st, voffA, voffB, qsrc);
          pf_wait(pf0, pf1);                 // prefetch issued last step; drained
          *(u4v*)(qtile + SW(gA_r, gA_c)) = st[0];
          *(u4v*)(qtile + SW(gB_r, gB_c)) = st[1];
          *(u4v*)(ptile + SW(gA_r, gA_c)) = pf0;
          *(u4v*)(ptile + SW(gB_r, gB_c)) = pf1;
        } else {
          u4v st[4];
          ld4_dual(st, voffA, voffB, qsrc, psrc);
          *(u4v*)(qtile + SW(gA_r, gA_c)) = st[0];
          *(u4v*)(qtile + SW(gB_r, gB_c)) = st[1];
          *(u4v*)(ptile + SW(gA_r, gA_c)) = st[2];
          *(u4v*)(ptile + SW(gB_r, gB_c)) = st[3];
        }
      } else if (t >= 1) {
        u4v st[2];
        ld2_sync(st, voffA, voffB, qsrc);
        *(u4v*)(qtile + SW(gA_r, gA_c)) = st[0];
        *(u4v*)(qtile + SW(gB_r, gB_c)) = st[1];
      } else if (lay > 0) {
        u4v st[2];
        ld2_sync(st, voffA, voffB, psrc);
        *(u4v*)(ptile + SW(gA_r, gA_c)) = st[0];
        *(u4v*)(ptile + SW(gB_r, gB_c)) = st[1];
      }
    }
    // issue next step's p-loads OUTSIDE the blocking window; their latency
    // hides under this step's MFMA + drain. Consumed (post tied-wait) at t+1.
    pfvalid = pnext;
    if (pnext) {
      const unsigned short* psrc2 = ring + (upring + ((t + 1) & (RD - 1))) * (MR * NN);
      ld2_async(pf0, pf1, voffA, voffB, psrc2);
    }
    __syncthreads();   // staging visible to all waves
    if (tid == 0 && lay > 0)   // upstream slot t consumed into LDS
      agent_st(doneline + ct, (unsigned)(t + 1));

    // ---- MFMA phase: q + p from swizzled LDS (t=0 q from h0) ----
    if (lay > 0) {
      #pragma unroll
      for (int kk = 0; kk < 16; ++kk) {
        s8v av = *(const s8v*)(ptile + SW(lo, kk * 4 + q4));
        accP = MFMA16(av, WI[kk], accP);
      }
    }
    if (t == 0) {
      const float* hsrc = h0 + (size_t)lay * BB * NN + (size_t)(row0 + lo) * NN + q4 * 8;
      #pragma unroll
      for (int kk = 0; kk < 16; ++kk) {
        f4v a = *(const f4v*)(hsrc + kk * 32);
        f4v b = *(const f4v*)(hsrc + kk * 32 + 4);
        s8v av = pack8(a, b);
        accQ = MFMA16(av, WH[kk], accQ);
      }
    } else {
      #pragma unroll
      for (int kk = 0; kk < 16; ++kk) {
        s8v av = *(const s8v*)(qtile + SW(lo, kk * 4 + q4));
        accQ = MFMA16(av, WH[kk], accQ);
      }
    }

    // ---- combine + produce: n = lrelu(0.5*h + 0.5*(q+p+x+bias)) ----
    {
      unsigned short* rslot = ring + (myring + (t & (RD - 1))) * (MR * NN);
      const int col = cw + lo;
      #pragma unroll
      for (int r = 0; r < 4; ++r) {
        const int row = q4 * 4 + r;
        float v2 = 0.5f * hst[r] + 0.5f * (accQ[r] + accP[r] + biasv);
        v2 = (v2 >= 0.f) ? v2 : 0.01f * v2;
        hst[r] = v2;
        stg_sc1_b16(rslot + (size_t)row * NN + col,
                    (unsigned)(unsigned short)f2bf(v2));
        if (lay == 2 && t == TS - 1)
          hfinal[(size_t)(row0 + row) * NN + col] = v2;
      }
    }

    // ---- xa loads for t+1 (latency hidden under the store drain) ----
    {
      const int tn = (t + 1 < TS) ? t + 1 : t;
      const float* dsrc = data + ((size_t)tn * BB + row0 + lo) * 64 + q4 * 8;
      xa0 = *(const f4v*)(dsrc + 0);
      xa1 = *(const f4v*)(dsrc + 4);
      xa2 = *(const f4v*)(dsrc + 32);
      xa3 = *(const f4v*)(dsrc + 36);
    }
    // drains payload stores + xa loads (+ any in-flight prefetch; its regs
    // are re-guarded by pf_wait before use next step)
    waitvm0();
    __syncthreads();   // every wave's stores drained -> publish
    if (tid == 0)
      agent_st(prodline + ct, (unsigned)(t + 1));
  }
}

// out[256,10] = hfinal @ Wfc + b_fc   (tiny f32 readout)
__global__ void readout_k(const float* __restrict__ hfinal, const float* __restrict__ Wfc,
                          const float* __restrict__ b_fc, float* __restrict__ out)
{
  const int row = blockIdx.x;
  const int lane = threadIdx.x;  // 64
  float a[10];
  #pragma unroll
  for (int c = 0; c < 10; ++c) a[c] = 0.f;
  for (int k = lane; k < NN; k += 64) {
    const float h = hfinal[(size_t)row * NN + k];
    const float* w = Wfc + (size_t)k * 10;
    #pragma unroll
    for (int c = 0; c < 10; ++c) a[c] += h * w[c];
  }
  #pragma unroll
  for (int off = 32; off > 0; off >>= 1) {
    #pragma unroll
    for (int c = 0; c < 10; ++c) a[c] += __shfl_down(a[c], off);
  }
  if (lane == 0) {
    #pragma unroll
    for (int c = 0; c < 10; ++c) out[row * 10 + c] = a[c] + b_fc[c];
  }
}

extern "C" void kernel_launch(void* const* d_in, const int* in_sizes, int n_in,
                              void* d_out, int out_size, void* d_ws, size_t ws_size,
                              hipStream_t stream) {
  (void)in_sizes; (void)n_in; (void)out_size; (void)ws_size;
  const float* data = (const float*)d_in[0];
  const float* h0   = (const float*)d_in[1];
  const float* Win  = (const float*)d_in[2];
  const float* b_in = (const float*)d_in[3];
  const float* Whh  = (const float*)d_in[4];
  const float* b_hh = (const float*)d_in[5];
  const float* Whi  = (const float*)d_in[6];
  const float* b_hi = (const float*)d_in[7];
  const float* Wfc  = (const float*)d_in[8];
  const float* b_fc = (const float*)d_in[9];

  // ws: rings (3 lay x 16 rg x RD x 16KB = 6 MB) | flags 64KB | hfinal 512KB
  unsigned short* ring = (unsigned short*)d_ws;
  const size_t ring_bytes = (size_t)3 * NRG * RD * MR * NN * 2;  // 6 MB
  unsigned* cnt = (unsigned*)((char*)d_ws + ring_bytes);
  float* hfinal = (float*)((char*)d_ws + ring_bytes + 65536);

  hipMemsetAsync(cnt, 0, 65536, stream);   // flags MUST start at 0 (ws is poisoned)
  hipLaunchKernelGGL(rnn_pipe, dim3(192), dim3(512), 0, stream,
                     data, h0, Win, b_in, Whh, b_hh, Whi, b_hi, ring, cnt, hfinal);
  hipLaunchKernelGGL(readout_k, dim3(256), dim3(64), 0, stream,
                     hfinal, Wfc, b_fc, (float*)d_out);
}